// Round 4
// baseline (2099.306 us; speedup 1.0000x reference)
//
#include <hip/hip_runtime.h>

// LTC RNN (LiquidNeuralNetwork): B=512, S=512, H=128, 2 layers, RK4.
// Round 6: LAYER-SPLIT ACROSS 64 BLOCKS (2x CUs). Round-3/5 counters showed the
// 32 active CUs at ~61% VALU / ~28% MFMA issue (GPU-wide 7.7/3.6 x 8), i.e.
// per-CU issue-bound; the (512,1) experiment refuted register starvation
// (compiler kept 128 VGPR, dur unchanged). Only lever: halve per-CU work.
//   - blocks 0..31 = layer 0 (producer), blocks 32..63 = layer 1 (consumer),
//     same batch group bg; each block: 8 waves x 1 row-tile (was 2).
//   - h0(t) [16x128 f16 = 4KB] streams via a 4-deep ring in d_ws using
//     agent-scope atomics (cross-XCD coherent). prod flag published one step
//     late after vmcnt(0) (stores provably complete); cons flag gives
//     backpressure. Deadlock-checked: consumer waits prod>=t+2 (pub at prod
//     D(t+2)); producer waits cons>=t-3 (pub at cons B(t-3) < its wait pt).
//   - prep_kernel zeroes flags every launch (graph-replay safe).
//   - gx/bg folded into MFMA C-operand init (kills ZACC+add per slot).
// Kept from earlier rounds: lgkm-only barriers, x-proj pipelined into slot B,
// f16 MFMA weight fragments packed once by prep_kernel.

typedef _Float16 f16;
typedef _Float16 f16x4 __attribute__((ext_vector_type(4)));
typedef _Float16 f16x8 __attribute__((ext_vector_type(8)));
typedef float f32x4 __attribute__((ext_vector_type(4)));
typedef unsigned long long u64;

#define NSTEP 512
#define OFF_A0 0
#define OFF_A1 32768
#define OFF_AIO 65536
#define OFF_AX 98304
#define W_TOTAL 122880

// workspace layout (bytes): W pack [0,245760); flags [245760,246016);
// ring [246272, 246272 + 32*RING_R*4096)
#define FLAGS_OFF 245760
#define RING_OFF 246272
#define RING_R 4
#define RING_PAIR_BYTES (RING_R * 4096)

// LDS byte offsets. hh buffers: [16 cols][136 f16] = 4352 B each.
#define HQ0 0
#define HQ1 4352
#define LBA 8704
#define LBB 13056
#define XT0 17408
#define XT1 19712
#define SMEM_BYTES 22272

__device__ __forceinline__ float rcp_f(float x) { return __builtin_amdgcn_rcpf(x); }
__device__ __forceinline__ float tanh_f(float x) {
  float e = __expf(2.f * x);
  return 1.f - 2.f * rcp_f(e + 1.f);
}
// sigmoid(t) for t in [-1,1] (t = tanh(...)): odd Taylor of 0.5+0.5*tanh(t/2), |err|<3e-6
__device__ __forceinline__ float sig_poly(float t) {
  float s = t * t;
  float p = fmaf(s, 2.1356861e-5f, -2.1081349e-4f);
  p = fmaf(s, p, 2.0833333e-3f);
  p = fmaf(s, p, -2.0833333e-2f);
  p = fmaf(s, p, 0.25f);
  return fmaf(t, p, 0.5f);
}

// lgkm-only barrier: LDS produce->consume needs lgkmcnt(0)+s_barrier only;
// does NOT drain vmcnt (global prefetches stay in flight). The "memory"
// clobber is the compiler fence that keeps loads/stores on their side.
#define BAR()                                            \
  do {                                                   \
    asm volatile("s_waitcnt lgkmcnt(0)" ::: "memory");   \
    __builtin_amdgcn_s_barrier();                        \
  } while (0)

// Pack all recurrent-loop weights into f16 MFMA A-fragments.
// A-frag (16x16x32): A[m=lane&15][k=(lane>>4)*8+j], row-tile T = rows 16T..16T+15.
// A0 @0      [T8][sel2][kc4][lane64][j8]  sel0=Wg0 h-part, sel1=Wrec0
// A1 @32768  same                          sel0=Wg1 h-part, sel1=Wrec1
// AIO@65536  same                          sel0=Win1,       sel1=Wg1 x-part
// AX @98304  [T8][sel2][kc3][lane64][j8]  sel0=Win0,       sel1=Wg0 x-part (K=96)
__global__ __launch_bounds__(256) void prep_kernel(
    const float* __restrict__ Win0, const float* __restrict__ Wrec0,
    const float* __restrict__ Wg0, const float* __restrict__ Win1,
    const float* __restrict__ Wrec1, const float* __restrict__ Wg1,
    f16* __restrict__ W) {
  // zero the sync flags every launch (graph replay re-runs this dispatch
  // before ltc_kernel on the same stream)
  if (blockIdx.x == 0 && threadIdx.x < 64)
    ((int*)((char*)W + FLAGS_OFF))[threadIdx.x] = 0;
  int i = blockIdx.x * 256 + threadIdx.x;
  if (i >= W_TOTAL) return;
  if (i < OFF_AX) {
    int sec = i >> 15;
    int r = i & 32767;
    int j = r & 7, lane = (r >> 3) & 63, kc = (r >> 9) & 3, sel = (r >> 11) & 1,
        w = (r >> 12) & 7;
    int row = w * 16 + (lane & 15);
    int k = kc * 32 + ((lane >> 4) << 3) + j;
    float v;
    if (sec == 0)
      v = sel ? Wrec0[row * 128 + k] : Wg0[row * 224 + 96 + k];
    else if (sec == 1)
      v = sel ? Wrec1[row * 128 + k] : Wg1[row * 256 + 128 + k];
    else
      v = sel ? Wg1[row * 256 + k] : Win1[row * 128 + k];
    W[i] = (f16)v;
  } else {
    int r = i - OFF_AX;
    int j = r & 7, lane = (r >> 3) & 63, g = r >> 9;
    int kc = g % 3, sg = g / 3;
    int sel = sg & 1, w = sg >> 1;
    int row = w * 16 + (lane & 15);
    int k = kc * 32 + ((lane >> 4) << 3) + j;
    W[i] = (f16)(sel ? Wg0[row * 224 + k] : Win0[row * 96 + k]);
  }
}

#define MFMA16(A, B, C) __builtin_amdgcn_mfma_f32_16x16x32_f16((A), (B), (C), 0, 0, 0)
#define ZERO4 ((f32x4){0.f, 0.f, 0.f, 0.f})

// recurrent matvec, gx folded into gate accumulator C-init:
// ga = gx + Wg_h*h ; ra = Wrec*h
#define MM2G(SRC)                                                   \
  {                                                                 \
    ga = gx; ra = ZERO4;                                            \
    const f16* bp_ = (SRC) + c * 136 + 8 * q;                       \
    _Pragma("unroll") for (int kc_ = 0; kc_ < 4; ++kc_) {           \
      f16x8 bf_ = *(const f16x8*)(bp_ + kc_ * 32);                  \
      ga = MFMA16(awg[kc_], bf_, ga);                               \
      ra = MFMA16(awr[kc_], bf_, ra);                               \
    }                                                               \
  }

// consumer io projection from prefetched h0(t) frags: u = Win1*h0,
// gx = Wg1x*h0 + bg (bg folded into C-init)
#define MMIO_PF()                                                   \
  {                                                                 \
    ga = ZERO4; ra = bgv;                                           \
    ga = MFMA16(au[0], pf0, ga); ra = MFMA16(ag2[0], pf0, ra);      \
    ga = MFMA16(au[1], pf1, ga); ra = MFMA16(ag2[1], pf1, ra);      \
    ga = MFMA16(au[2], pf2, ga); ra = MFMA16(ag2[2], pf2, ra);      \
    ga = MFMA16(au[3], pf3, ga); ra = MFMA16(ag2[3], pf3, ra);      \
    u = ga; gx = ra;                                                \
  }

// producer x-projection (K=96: 2 chunks from x-tile + ctx), bg folded
#define XPROJ(XSRC, UD, GD)                                         \
  {                                                                 \
    f32x4 tg_ = ZERO4, tr_ = bgv;                                   \
    f16x8 bx0_ = *(const f16x8*)((XSRC) + c * 72 + 8 * q);          \
    f16x8 bx1_ = *(const f16x8*)((XSRC) + c * 72 + 32 + 8 * q);     \
    tg_ = MFMA16(au[0], bx0_, tg_); tr_ = MFMA16(ag2[0], bx0_, tr_);\
    tg_ = MFMA16(au[1], bx1_, tg_); tr_ = MFMA16(ag2[1], bx1_, tr_);\
    tg_ = MFMA16(au[2], bctx, tg_); tr_ = MFMA16(ag2[2], bctx, tr_);\
    (UD) = tg_; (GD) = tr_;                                         \
  }

// RK stage body (gate arg already complete in ga)
#define GATEALL(WC, HC, DST)                                        \
  {                                                                 \
    f16x4 hv_;                                                      \
    _Pragma("unroll") for (int r_ = 0; r_ < 4; ++r_) {              \
      float th_ = tanh_f(ga[r_]);                                   \
      float gt_ = sig_poly(th_);                                    \
      float kk_ = fmaf(gt_, ra[r_],                                 \
                       fmaf(-itv[r_], hhc[r_], u[r_]));             \
      ksum[r_] = fmaf((WC), kk_, ksum[r_]);                         \
      float hn_ = fmaf((HC), kk_, hst[r_]);                         \
      hhc[r_] = hn_;                                                \
      hv_[r_] = (f16)hn_;                                           \
    }                                                               \
    *(f16x4*)((DST) + c * 136 + jbase) = hv_;                       \
  }

// consumer ring prefetch: two 8B agent-relaxed atomic loads per k-chunk
#define LDPF8(KC_, DST_)                                                      \
  {                                                                           \
    u64* p_ = (u64*)(rs_ + c * 128 + (KC_) * 32 + 8 * q);                     \
    u64 lo_ = __hip_atomic_load(p_, __ATOMIC_RELAXED, __HIP_MEMORY_SCOPE_AGENT); \
    u64 hi_ = __hip_atomic_load(p_ + 1, __ATOMIC_RELAXED, __HIP_MEMORY_SCOPE_AGENT); \
    union { u64 v[2]; f16x8 f; } uu_;                                         \
    uu_.v[0] = lo_; uu_.v[1] = hi_;                                           \
    DST_ = uu_.f;                                                             \
  }
#define LOADPF(M_)                                                  \
  {                                                                 \
    f16* rs_ = ring + ((M_) & (RING_R - 1)) * 2048;                 \
    LDPF8(0, pf0); LDPF8(1, pf1); LDPF8(2, pf2); LDPF8(3, pf3);     \
  }

__global__ __launch_bounds__(512, 1) void ltc_kernel(
    const float* __restrict__ seq, const float* __restrict__ ctx,
    const float* __restrict__ tau0p, const float* __restrict__ bg0p,
    const float* __restrict__ tau1p, const float* __restrict__ bg1p,
    const float* __restrict__ W1, const float* __restrict__ b1,
    const float* __restrict__ W2, const float* __restrict__ b2,
    const f16* __restrict__ W, char* __restrict__ ws,
    float* __restrict__ out) {
  __shared__ __align__(16) char smem[SMEM_BYTES];
  f16* hq0 = (f16*)(smem + HQ0);
  f16* hq1 = (f16*)(smem + HQ1);
  f16* bufA = (f16*)(smem + LBA);
  f16* bufB = (f16*)(smem + LBB);
  f16* xt0 = (f16*)(smem + XT0);
  f16* xt1 = (f16*)(smem + XT1);

  const int tid = threadIdx.x;
  const int w8 = tid >> 6, lane = tid & 63;
  const int q = lane >> 4, c = lane & 15;
  const bool isProd = (blockIdx.x < 32);
  const int bg = isProd ? blockIdx.x : blockIdx.x - 32;
  const int jbase = 16 * w8 + 4 * q;  // this wave's 16-row tile, lane's 4 rows

  int* prodf = (int*)(ws + FLAGS_OFF) + bg;
  int* consf = (int*)(ws + FLAGS_OFF + 128) + bg;
  f16* ring = (f16*)(ws + RING_OFF + (size_t)bg * RING_PAIR_BYTES);

  // ---- weight fragments -> VGPRs (held for whole kernel) ----
  f16x8 awg[4], awr[4], au[4], ag2[4];
  f16x8 bctx = (f16x8)(f16)0.f;
  if (isProd) {
#pragma unroll
    for (int kc = 0; kc < 4; ++kc) {
      awg[kc] = *(const f16x8*)(W + OFF_A0 + (((w8 * 2 + 0) * 4 + kc) * 64 + lane) * 8);
      awr[kc] = *(const f16x8*)(W + OFF_A0 + (((w8 * 2 + 1) * 4 + kc) * 64 + lane) * 8);
    }
#pragma unroll
    for (int kc = 0; kc < 3; ++kc) {
      au[kc] = *(const f16x8*)(W + OFF_AX + (((w8 * 2 + 0) * 3 + kc) * 64 + lane) * 8);
      ag2[kc] = *(const f16x8*)(W + OFF_AX + (((w8 * 2 + 1) * 3 + kc) * 64 + lane) * 8);
    }
    au[3] = (f16x8)(f16)0.f;
    ag2[3] = (f16x8)(f16)0.f;
    const float* cp = ctx + (bg * 16 + c) * 32 + 8 * q;
#pragma unroll
    for (int j = 0; j < 8; ++j) bctx[j] = (f16)cp[j];
  } else {
#pragma unroll
    for (int kc = 0; kc < 4; ++kc) {
      awg[kc] = *(const f16x8*)(W + OFF_A1 + (((w8 * 2 + 0) * 4 + kc) * 64 + lane) * 8);
      awr[kc] = *(const f16x8*)(W + OFF_A1 + (((w8 * 2 + 1) * 4 + kc) * 64 + lane) * 8);
      au[kc] = *(const f16x8*)(W + OFF_AIO + (((w8 * 2 + 0) * 4 + kc) * 64 + lane) * 8);
      ag2[kc] = *(const f16x8*)(W + OFF_AIO + (((w8 * 2 + 1) * 4 + kc) * 64 + lane) * 8);
    }
  }

  // per-lane params for the 4 owned rows
  const float* taup = isProd ? tau0p : tau1p;
  const float* bgp = isProd ? bg0p : bg1p;
  f32x4 itv, bgv;
#pragma unroll
  for (int r = 0; r < 4; ++r) {
    float t = taup[jbase + r];
    itv[r] = 1.f / (logf(1.f + __expf(t)) + 1.f);  // 1/(softplus+1)
    bgv[r] = bgp[jbase + r];
  }

  f32x4 hst = ZERO4, hhc = ZERO4, u = ZERO4, gx = ZERO4, ksum = ZERO4;
  f32x4 ga, ra, un = ZERO4, gxn = ZERO4;
  f16x8 pf0, pf1, pf2, pf3;

  // zero initial-state buffer hq1 (state at t=-1)
  for (int j = tid; j < 2176; j += 512) hq1[j] = (f16)0.f;

  const int bs = tid >> 4, fp = tid & 15;
  const size_t seqrow = ((size_t)(bg * 16 + bs)) * NSTEP * 64 + 4 * fp;
  float4 sq_nxt = {0.f, 0.f, 0.f, 0.f};
  float4 sq_ld = sq_nxt;

  if (isProd) {
    // ================== producer: layer 0 ==================
    if (tid < 256) {
      float4 sv = *(const float4*)(seq + seqrow);
      *(f16x4*)(xt0 + bs * 72 + 4 * fp) =
          (f16x4){(f16)sv.x, (f16)sv.y, (f16)sv.z, (f16)sv.w};
      sq_nxt = *(const float4*)(seq + seqrow + 64);  // x(1)
    }
    __syncthreads();
    XPROJ(xt0, u, gx);  // u/gx for step 0

#pragma unroll 1
    for (int i = 0; i < NSTEP; ++i) {
      const f16* hprev = ((i + 1) & 1) ? hq1 : hq0;
      f16* xw = ((i + 1) & 1) ? xt1 : xt0;
      // ---- slot A: stage 1 on h0(i-1); stage x(i+1); issue x(i+2) ----
      if (tid < 256 && i + 2 < NSTEP)
        sq_ld = *(const float4*)(seq + seqrow + (size_t)(i + 2) * 64);
      MM2G(hprev);
      if (tid < 256 && i + 1 < NSTEP)
        *(f16x4*)(xw + bs * 72 + 4 * fp) =
            (f16x4){(f16)sq_nxt.x, (f16)sq_nxt.y, (f16)sq_nxt.z, (f16)sq_nxt.w};
      ksum = ZERO4;
      GATEALL(1.0f, 0.5f, bufA);
      BAR();
      // ---- slot B: stage 2; x-proj(i+1) off-path ----
      MM2G(bufA);
      GATEALL(2.0f, 0.5f, bufB);
      if (i + 1 < NSTEP) { XPROJ(xw, un, gxn); }
      BAR();
      // ---- slot C: stage 3; backpressure poll; drain ring stores ----
      MM2G(bufB);
      GATEALL(2.0f, 1.0f, bufA);
      if (tid == 0 && i >= RING_R)
        while (__hip_atomic_load(consf, __ATOMIC_ACQUIRE, __HIP_MEMORY_SCOPE_AGENT) <
               i - RING_R + 1)
          __builtin_amdgcn_s_sleep(2);
      asm volatile("s_waitcnt vmcnt(0)" ::: "memory");  // step i-1 ring stores done
      BAR();
      // ---- slot D: publish h0(<=i-1); stage 4 -> h0(i); ring store ----
      if (tid == 0)
        __hip_atomic_store(prodf, i, __ATOMIC_RELEASE, __HIP_MEMORY_SCOPE_AGENT);
      MM2G(bufA);
      {
        f16x4 hv_;
#pragma unroll
        for (int r_ = 0; r_ < 4; ++r_) {
          float th_ = tanh_f(ga[r_]);
          float gt_ = sig_poly(th_);
          float kk_ = fmaf(gt_, ra[r_], fmaf(-itv[r_], hhc[r_], u[r_]));
          float ks_ = ksum[r_] + kk_;
          float hn_ = tanh_f(fmaf(ks_, 0.16666667f, hst[r_]));
          hst[r_] = hn_;
          hhc[r_] = hn_;
          hv_[r_] = (f16)hn_;
        }
        *(f16x4*)(((i & 1) ? hq1 : hq0) + c * 136 + jbase) = hv_;
        u64 hb_;
        __builtin_memcpy(&hb_, &hv_, 8);
        __hip_atomic_store((u64*)(ring + (i & (RING_R - 1)) * 2048 + c * 128 + jbase),
                           hb_, __ATOMIC_RELAXED, __HIP_MEMORY_SCOPE_AGENT);
      }
      u = un;
      gx = gxn;
      if (i + 2 < NSTEP) sq_nxt = sq_ld;
      BAR();
    }
    // final publish: h0(0..511) all visible
    asm volatile("s_waitcnt vmcnt(0)" ::: "memory");
    __syncthreads();
    if (tid == 0)
      __hip_atomic_store(prodf, NSTEP, __ATOMIC_RELEASE, __HIP_MEMORY_SCOPE_AGENT);
    return;
  }

  // ================== consumer: layer 1 ==================
  if (tid == 0)
    while (__hip_atomic_load(prodf, __ATOMIC_ACQUIRE, __HIP_MEMORY_SCOPE_AGENT) < 1)
      __builtin_amdgcn_s_sleep(2);
  __syncthreads();
  LOADPF(0);

#pragma unroll 1
  for (int i = 0; i < NSTEP; ++i) {
    const f16* hprev = ((i + 1) & 1) ? hq1 : hq0;  // h1(i-1)
    // ---- slot A: io-proj from h0(i); stage 1 on h1(i-1) ----
    MMIO_PF();
    MM2G(hprev);
    ksum = ZERO4;
    GATEALL(1.0f, 0.5f, bufA);
    BAR();
    // ---- slot B: publish consumption; stage 2 ----
    if (tid == 0)
      __hip_atomic_store(consf, i + 1, __ATOMIC_RELEASE, __HIP_MEMORY_SCOPE_AGENT);
    MM2G(bufA);
    GATEALL(2.0f, 0.5f, bufB);
    BAR();
    // ---- slot C: stage 3; poll for h0(i+1) ----
    MM2G(bufB);
    GATEALL(2.0f, 1.0f, bufA);
    if (tid == 0 && i + 1 < NSTEP)
      while (__hip_atomic_load(prodf, __ATOMIC_ACQUIRE, __HIP_MEMORY_SCOPE_AGENT) <
             i + 2)
        __builtin_amdgcn_s_sleep(2);
    BAR();
    // ---- slot D: stage 4 -> h1(i); prefetch h0(i+1) ----
    MM2G(bufA);
    {
      f16x4 hv_;
#pragma unroll
      for (int r_ = 0; r_ < 4; ++r_) {
        float th_ = tanh_f(ga[r_]);
        float gt_ = sig_poly(th_);
        float kk_ = fmaf(gt_, ra[r_], fmaf(-itv[r_], hhc[r_], u[r_]));
        float ks_ = ksum[r_] + kk_;
        float hn_ = tanh_f(fmaf(ks_, 0.16666667f, hst[r_]));
        hst[r_] = hn_;
        hhc[r_] = hn_;
        hv_[r_] = (f16)hn_;
      }
      *(f16x4*)(((i & 1) ? hq1 : hq0) + c * 136 + jbase) = hv_;
    }
    if (i + 1 < NSTEP) { LOADPF(i + 1); }
    BAR();
  }

  // ======================= classifier epilogue (consumer) ================
  float* h1f = (float*)smem;  // [16][132] f32
  *(f32x4*)(h1f + c * 132 + jbase) = hst;
  __syncthreads();
  float* z1 = (float*)(smem + 16 * 132 * 4);  // [16][64] f32
  {
    int b = tid >> 5, o = tid & 31;
#pragma unroll
    for (int hlf = 0; hlf < 2; ++hlf) {
      int oo = o + 32 * hlf;
      const float* wr = W1 + oo * 128;
      const float* hr = h1f + b * 132;
      float s = 0.f;
#pragma unroll
      for (int j = 0; j < 128; j += 4) {
        f32x4 wv = *(const f32x4*)(wr + j);
        f32x4 hv = *(const f32x4*)(hr + j);
        s += wv[0] * hv[0] + wv[1] * hv[1] + wv[2] * hv[2] + wv[3] * hv[3];
      }
      s += b1[oo];
      z1[b * 64 + oo] = fmaxf(s, 0.f);
    }
  }
  __syncthreads();
  if (tid < 16) {
    float s = b2[0];
#pragma unroll
    for (int o = 0; o < 64; ++o) s += z1[tid * 64 + o] * W2[o];
    out[bg * 16 + tid] = rcp_f(1.f + __expf(-s));
  }
}

extern "C" void kernel_launch(void* const* d_in, const int* in_sizes, int n_in,
                              void* d_out, int out_size, void* d_ws, size_t ws_size,
                              hipStream_t stream) {
  (void)in_sizes; (void)n_in; (void)out_size; (void)ws_size;
  const float* seq = (const float*)d_in[0];
  const float* ctx = (const float*)d_in[1];
  const float* tau0 = (const float*)d_in[2];
  const float* Win0 = (const float*)d_in[3];
  const float* Wrec0 = (const float*)d_in[4];
  const float* Wg0 = (const float*)d_in[5];
  const float* bg0 = (const float*)d_in[6];
  const float* tau1 = (const float*)d_in[7];
  const float* Win1 = (const float*)d_in[8];
  const float* Wrec1 = (const float*)d_in[9];
  const float* Wg1 = (const float*)d_in[10];
  const float* bg1 = (const float*)d_in[11];
  const float* W1 = (const float*)d_in[12];
  const float* b1 = (const float*)d_in[13];
  const float* W2 = (const float*)d_in[14];
  const float* b2 = (const float*)d_in[15];
  f16* W = (f16*)d_ws;  // 245760 B packed fragments + flags + h0 ring

  prep_kernel<<<480, 256, 0, stream>>>(Win0, Wrec0, Wg0, Win1, Wrec1, Wg1, W);
  ltc_kernel<<<64, 512, 0, stream>>>(seq, ctx, tau0, bg0, tau1, bg1, W1, b1, W2,
                                     b2, W, (char*)d_ws, (float*)d_out);
}

// Round 5
// 1912.067 us; speedup vs baseline: 1.0979x; 1.0979x over previous
//
#include <hip/hip_runtime.h>

// LTC RNN (LiquidNeuralNetwork): B=512, S=512, H=128, 2 layers, RK4.
// Round 7: BATCH-SPLIT to 64 blocks x 8 batch-cols (was 32 x 16).
// Round-3 counters: active CUs at ~61% VALU + ~28% MFMA issue (88% packed) ->
// per-CU issue-bound. Round-6 (layer-split) proved cross-block streaming costs
// more than it saves (agent atomics bypass XCD L2 -> 66 MB HBM writes, +800
// cy/step). Batch groups are fully independent -> split them instead: per-CU
// gate-VALU halves (~1320 -> ~660 cy/slot), MFMA pipe stays ~610 cy (B-frag 16
// wide; cols 8-15 dead but matrix pipe has headroom). No new sync.
// Dead cols are NaN-isolated (MFMA col j reads only B col j); dead xt rows are
// zeroed at init; global reads indexed by c are clamped (c&7) to stay in-bounds.
// Kept: lag-1 layer pipeline (waves 0-3 L0 @t, 4-7 L1 @t-1), 4 slots/step,
// lgkm-only barriers, x-proj pipelined into slot B, f16 MFMA fragment pack.

typedef _Float16 f16;
typedef _Float16 f16x4 __attribute__((ext_vector_type(4)));
typedef _Float16 f16x8 __attribute__((ext_vector_type(8)));
typedef float f32x4 __attribute__((ext_vector_type(4)));

#define NSTEP 512
#define BPG 8  // batch rows per block
#define OFF_A0 0
#define OFF_A1 32768
#define OFF_AIO 65536
#define OFF_AX 98304
#define W_TOTAL 122880

// LDS byte offsets. hh buffers: [16 cols][136 f16] = 4352 B each.
#define HQ0 0
#define HQ1 4352
#define L0A 8704
#define L0B 13056
#define L1A 17408
#define L1B 21760
#define L1H 26112
#define XT0 30464
#define XT1 32768
#define SMEM_BYTES 35072

__device__ __forceinline__ float rcp_f(float x) { return __builtin_amdgcn_rcpf(x); }
__device__ __forceinline__ float tanh_f(float x) {
  float e = __expf(2.f * x);
  return 1.f - 2.f * rcp_f(e + 1.f);
}
// sigmoid(t) for t in [-1,1] (t = tanh(...)): odd Taylor of 0.5+0.5*tanh(t/2), |err|<3e-6
__device__ __forceinline__ float sig_poly(float t) {
  float s = t * t;
  float p = fmaf(s, 2.1356861e-5f, -2.1081349e-4f);
  p = fmaf(s, p, 2.0833333e-3f);
  p = fmaf(s, p, -2.0833333e-2f);
  p = fmaf(s, p, 0.25f);
  return fmaf(t, p, 0.5f);
}

// lgkm-only barrier: LDS produce->consume needs lgkmcnt(0)+s_barrier only;
// does NOT drain vmcnt (seq prefetch stays in flight across barriers).
#define BAR()                                            \
  do {                                                   \
    asm volatile("s_waitcnt lgkmcnt(0)" ::: "memory");   \
    __builtin_amdgcn_s_barrier();                        \
  } while (0)

// Pack all recurrent-loop weights into f16 MFMA A-fragments.
// A-frag (16x16x32): A[m=lane&15][k=(lane>>4)*8+j], row-tile T = rows 16T..16T+15.
// A0 @0      [T8][sel2][kc4][lane64][j8]  sel0=Wg0 h-part, sel1=Wrec0
// A1 @32768  same                          sel0=Wg1 h-part, sel1=Wrec1
// AIO@65536  same                          sel0=Win1,       sel1=Wg1 x-part
// AX @98304  [T8][sel2][kc3][lane64][j8]  sel0=Win0,       sel1=Wg0 x-part (K=96)
__global__ __launch_bounds__(256) void prep_kernel(
    const float* __restrict__ Win0, const float* __restrict__ Wrec0,
    const float* __restrict__ Wg0, const float* __restrict__ Win1,
    const float* __restrict__ Wrec1, const float* __restrict__ Wg1,
    f16* __restrict__ W) {
  int i = blockIdx.x * 256 + threadIdx.x;
  if (i >= W_TOTAL) return;
  if (i < OFF_AX) {
    int sec = i >> 15;
    int r = i & 32767;
    int j = r & 7, lane = (r >> 3) & 63, kc = (r >> 9) & 3, sel = (r >> 11) & 1,
        w = (r >> 12) & 7;
    int row = w * 16 + (lane & 15);
    int k = kc * 32 + ((lane >> 4) << 3) + j;
    float v;
    if (sec == 0)
      v = sel ? Wrec0[row * 128 + k] : Wg0[row * 224 + 96 + k];
    else if (sec == 1)
      v = sel ? Wrec1[row * 128 + k] : Wg1[row * 256 + 128 + k];
    else
      v = sel ? Wg1[row * 256 + k] : Win1[row * 128 + k];
    W[i] = (f16)v;
  } else {
    int r = i - OFF_AX;
    int j = r & 7, lane = (r >> 3) & 63, g = r >> 9;
    int kc = g % 3, sg = g / 3;
    int sel = sg & 1, w = sg >> 1;
    int row = w * 16 + (lane & 15);
    int k = kc * 32 + ((lane >> 4) << 3) + j;
    W[i] = (f16)(sel ? Wg0[row * 224 + k] : Win0[row * 96 + k]);
  }
}

#define MFMA16(A, B, C) __builtin_amdgcn_mfma_f32_16x16x32_f16((A), (B), (C), 0, 0, 0)
#define ZERO4 ((f32x4){0.f, 0.f, 0.f, 0.f})

// 2-tile matvec accumulate: ga/ra[i2] += {awg,awr}[i2] * B-frag(SRC). One B-frag
// read feeds 4 MFMAs.
#define MM2(SRC)                                                    \
  {                                                                 \
    const f16* bp_ = (SRC) + c * 136 + 8 * q;                       \
    _Pragma("unroll") for (int kc_ = 0; kc_ < 4; ++kc_) {           \
      f16x8 bf_ = *(const f16x8*)(bp_ + kc_ * 32);                  \
      ga[0] = MFMA16(awg[0][kc_], bf_, ga[0]);                      \
      ra[0] = MFMA16(awr[0][kc_], bf_, ra[0]);                      \
      ga[1] = MFMA16(awg[1][kc_], bf_, ga[1]);                      \
      ra[1] = MFMA16(awr[1][kc_], bf_, ra[1]);                      \
    }                                                               \
  }

// io / input projection with the au/ag2 fragment set (KCN k-chunks) into ga/ra.
#define MMIO(SRC, KCN)                                              \
  {                                                                 \
    const f16* bp_ = (SRC) + c * 136 + 8 * q;                       \
    _Pragma("unroll") for (int kc_ = 0; kc_ < (KCN); ++kc_) {       \
      f16x8 bf_ = *(const f16x8*)(bp_ + kc_ * 32);                  \
      ga[0] = MFMA16(au[0][kc_], bf_, ga[0]);                       \
      ra[0] = MFMA16(ag2[0][kc_], bf_, ra[0]);                      \
      ga[1] = MFMA16(au[1][kc_], bf_, ga[1]);                       \
      ra[1] = MFMA16(ag2[1][kc_], bf_, ra[1]);                      \
    }                                                               \
  }

// L0 x-projection (K=96: 2 chunks from x-tile + ctx) -> UD (=Win0*x),
// GD (=Wg0x*x + bg). Uses ga/ra as temporaries; off the recurrent path.
#define XPROJ(XSRC, UD, GD)                                         \
  {                                                                 \
    ZACC;                                                           \
    f16x8 bx0_ = *(const f16x8*)((XSRC) + c * 72 + 8 * q);          \
    f16x8 bx1_ = *(const f16x8*)((XSRC) + c * 72 + 32 + 8 * q);     \
    _Pragma("unroll") for (int i2_ = 0; i2_ < 2; ++i2_) {           \
      ga[i2_] = MFMA16(au[i2_][0], bx0_, ga[i2_]);                  \
      ra[i2_] = MFMA16(ag2[i2_][0], bx0_, ra[i2_]);                 \
      ga[i2_] = MFMA16(au[i2_][1], bx1_, ga[i2_]);                  \
      ra[i2_] = MFMA16(ag2[i2_][1], bx1_, ra[i2_]);                 \
      ga[i2_] = MFMA16(au[i2_][2], bctx, ga[i2_]);                  \
      ra[i2_] = MFMA16(ag2[i2_][2], bctx, ra[i2_]);                 \
      (UD)[i2_] = ga[i2_];                                          \
      _Pragma("unroll") for (int r_ = 0; r_ < 4; ++r_)              \
        (GD)[i2_][r_] = ra[i2_][r_] + bgv[i2_][r_];                 \
    }                                                               \
  }

// RK stage body: gate math on 8 (gate,rec) pairs, ksum += WC*k, eval point
// hhc = h + HC*k, write f16 eval point to DST.
#define GATEALL(WC, HC, DST)                                        \
  _Pragma("unroll") for (int i2_ = 0; i2_ < 2; ++i2_) {             \
    f16x4 hv_;                                                      \
    _Pragma("unroll") for (int r_ = 0; r_ < 4; ++r_) {              \
      float th_ = tanh_f(ga[i2_][r_] + gx[i2_][r_]);                \
      float gt_ = sig_poly(th_);                                    \
      float kk_ = fmaf(gt_, ra[i2_][r_],                            \
                       fmaf(-itv[i2_][r_], hhc[i2_][r_], u[i2_][r_])); \
      ksum[i2_][r_] = fmaf((WC), kk_, ksum[i2_][r_]);               \
      float hn_ = fmaf((HC), kk_, hst[i2_][r_]);                    \
      hhc[i2_][r_] = hn_;                                           \
      hv_[r_] = (f16)hn_;                                           \
    }                                                               \
    *(f16x4*)((DST) + c * 136 + jb[i2_]) = hv_;                     \
  }

// RK stage 4: h_new = tanh(h + ksum/6), becomes both state and next stage-1 eval.
#define GATEFIN(DST)                                                \
  _Pragma("unroll") for (int i2_ = 0; i2_ < 2; ++i2_) {             \
    f16x4 hv_;                                                      \
    _Pragma("unroll") for (int r_ = 0; r_ < 4; ++r_) {              \
      float th_ = tanh_f(ga[i2_][r_] + gx[i2_][r_]);                \
      float gt_ = sig_poly(th_);                                    \
      float kk_ = fmaf(gt_, ra[i2_][r_],                            \
                       fmaf(-itv[i2_][r_], hhc[i2_][r_], u[i2_][r_])); \
      float ks_ = ksum[i2_][r_] + kk_;                              \
      float hn_ = tanh_f(fmaf(ks_, 0.16666667f, hst[i2_][r_]));     \
      hst[i2_][r_] = hn_;                                           \
      hhc[i2_][r_] = hn_;                                           \
      hv_[r_] = (f16)hn_;                                           \
    }                                                               \
    *(f16x4*)((DST) + c * 136 + jb[i2_]) = hv_;                     \
  }

#define ZACC { ga[0] = ZERO4; ra[0] = ZERO4; ga[1] = ZERO4; ra[1] = ZERO4; }

__global__ __launch_bounds__(512, 1) void ltc_kernel(
    const float* __restrict__ seq, const float* __restrict__ ctx,
    const float* __restrict__ tau0p, const float* __restrict__ bg0p,
    const float* __restrict__ tau1p, const float* __restrict__ bg1p,
    const float* __restrict__ W1, const float* __restrict__ b1,
    const float* __restrict__ W2, const float* __restrict__ b2,
    const f16* __restrict__ W, float* __restrict__ out) {
  __shared__ __align__(16) char smem[SMEM_BYTES];
  f16* hq0 = (f16*)(smem + HQ0);
  f16* hq1 = (f16*)(smem + HQ1);
  f16* l0a = (f16*)(smem + L0A);
  f16* l0b = (f16*)(smem + L0B);
  f16* l1a = (f16*)(smem + L1A);
  f16* l1b = (f16*)(smem + L1B);
  f16* l1h = (f16*)(smem + L1H);
  f16* xt0 = (f16*)(smem + XT0);
  f16* xt1 = (f16*)(smem + XT1);

  const int tid = threadIdx.x;
  const int w8 = tid >> 6, lane = tid & 63;
  const int q = lane >> 4, c = lane & 15;
  const int wl = w8 & 3;
  const bool isL0 = (w8 < 4);
  const int bg = blockIdx.x;
  int jb[2];
  jb[0] = 32 * wl + 4 * q;
  jb[1] = jb[0] + 16;

  f16* bufA = isL0 ? l0a : l1a;
  f16* bufB = isL0 ? l0b : l1b;

  // ---- weight fragments -> VGPRs (held for whole kernel) ----
  f16x8 awg[2][4], awr[2][4], au[2][4], ag2[2][4];
  f16x8 bctx;
  if (isL0) {
#pragma unroll
    for (int i2 = 0; i2 < 2; ++i2) {
      int T = 2 * wl + i2;
#pragma unroll
      for (int kc = 0; kc < 4; ++kc) {
        awg[i2][kc] = *(const f16x8*)(W + OFF_A0 + (((T * 2 + 0) * 4 + kc) * 64 + lane) * 8);
        awr[i2][kc] = *(const f16x8*)(W + OFF_A0 + (((T * 2 + 1) * 4 + kc) * 64 + lane) * 8);
      }
#pragma unroll
      for (int kc = 0; kc < 3; ++kc) {
        au[i2][kc] = *(const f16x8*)(W + OFF_AX + (((T * 2 + 0) * 3 + kc) * 64 + lane) * 8);
        ag2[i2][kc] = *(const f16x8*)(W + OFF_AX + (((T * 2 + 1) * 3 + kc) * 64 + lane) * 8);
      }
      au[i2][3] = (f16x8)(f16)0.f;
      ag2[i2][3] = (f16x8)(f16)0.f;
    }
    // c&7 clamp: cols 8-15 are dead (BPG=8) but must not read OOB
    const float* cp = ctx + (bg * BPG + (c & 7)) * 32 + 8 * q;
#pragma unroll
    for (int j = 0; j < 8; ++j) bctx[j] = (f16)cp[j];
  } else {
#pragma unroll
    for (int i2 = 0; i2 < 2; ++i2) {
      int T = 2 * wl + i2;
#pragma unroll
      for (int kc = 0; kc < 4; ++kc) {
        awg[i2][kc] = *(const f16x8*)(W + OFF_A1 + (((T * 2 + 0) * 4 + kc) * 64 + lane) * 8);
        awr[i2][kc] = *(const f16x8*)(W + OFF_A1 + (((T * 2 + 1) * 4 + kc) * 64 + lane) * 8);
        au[i2][kc] = *(const f16x8*)(W + OFF_AIO + (((T * 2 + 0) * 4 + kc) * 64 + lane) * 8);
        ag2[i2][kc] = *(const f16x8*)(W + OFF_AIO + (((T * 2 + 1) * 4 + kc) * 64 + lane) * 8);
      }
    }
  }

  // per-lane params for the 8 owned rows
  const float* taup = isL0 ? tau0p : tau1p;
  const float* bgp = isL0 ? bg0p : bg1p;
  f32x4 itv[2], bgv[2];
#pragma unroll
  for (int i2 = 0; i2 < 2; ++i2)
#pragma unroll
    for (int r = 0; r < 4; ++r) {
      float t = taup[jb[i2] + r];
      itv[i2][r] = 1.f / (logf(1.f + __expf(t)) + 1.f);  // 1/(softplus+1)
      bgv[i2][r] = bgp[jb[i2] + r];
    }

  f32x4 hst[2], hhc[2], u[2], gx[2], ksum[2], ga[2], ra[2];
  f32x4 un[2], gxn[2];
  hst[0] = hst[1] = hhc[0] = hhc[1] = ZERO4;
  ksum[0] = ksum[1] = ZERO4;
  un[0] = un[1] = gxn[0] = gxn[1] = ZERO4;

  // zero initial-state buffers: hq1 (h0 at t=-1) and l1h (h1 at t=-1)
  for (int j = tid; j < 2176; j += 512) {
    hq1[j] = (f16)0.f;
    l1h[j] = (f16)0.f;
  }
  // zero dead xt rows 8-15 of both buffers (written once; staging never
  // touches them) so dead-col MFMA inputs are finite
  for (int j = tid; j < 576; j += 512) {
    xt0[576 + j] = (f16)0.f;
    xt1[576 + j] = (f16)0.f;
  }
  // pre-stage x(0): 128 threads (8 batch rows x 16 float4 chunks)
  const int bs = tid >> 4, fp = tid & 15;
  const size_t seqrow = ((size_t)(bg * BPG + bs)) * NSTEP * 64 + 4 * fp;
  float4 sq_nxt = {0.f, 0.f, 0.f, 0.f};
  float4 sq_ld = sq_nxt;
  if (tid < 16 * BPG) {
    float4 sv = *(const float4*)(seq + seqrow);
    *(f16x4*)(xt0 + bs * 72 + 4 * fp) =
        (f16x4){(f16)sv.x, (f16)sv.y, (f16)sv.z, (f16)sv.w};
    sq_nxt = *(const float4*)(seq + seqrow + 64);  // x(1)
  }
  __syncthreads();
  // u/gx for step 0 (pipeline warm-up)
  if (isL0) { XPROJ(xt0, u, gx); }

#pragma unroll 1
  for (int i = 0; i <= NSTEP; ++i) {
    const f16* hprev = ((i + 1) & 1) ? hq1 : hq0;  // h0(t-1) buffer
    f16* xw = ((i + 1) & 1) ? xt1 : xt0;           // buffer for x(i+1)

    // ===== slot A: L0 stage1 (+stage x(i+1), issue x(i+2)) | L1 io + stage1
    if (isL0) {
      if (i < NSTEP) {
        if (tid < 16 * BPG && i + 2 < NSTEP)
          sq_ld = *(const float4*)(seq + seqrow + (size_t)(i + 2) * 64);
        ZACC;
        MM2(hprev);  // stage 1 on h0(t-1) -- the critical prefix
        if (tid < 16 * BPG && i + 1 < NSTEP)
          *(f16x4*)(xw + bs * 72 + 4 * fp) =
              (f16x4){(f16)sq_nxt.x, (f16)sq_nxt.y, (f16)sq_nxt.z, (f16)sq_nxt.w};
        ksum[0] = ZERO4; ksum[1] = ZERO4;
        GATEALL(1.0f, 0.5f, bufA);
      }
    } else {
      if (i >= 1) {
        ZACC;
        MMIO(hprev, 4);  // u1 = Win1*h0_new, g1x = Wg1x*h0_new
#pragma unroll
        for (int i2 = 0; i2 < 2; ++i2) {
          u[i2] = ga[i2];
#pragma unroll
          for (int r = 0; r < 4; ++r) gx[i2][r] = ra[i2][r] + bgv[i2][r];
        }
        ZACC;
        MM2(l1h);  // stage 1 on h1(t-2)
        ksum[0] = ZERO4; ksum[1] = ZERO4;
        GATEALL(1.0f, 0.5f, bufA);
      }
    }
    BAR();

    // ===== slot B: stage 2 ; L0 also computes x-proj(i+1) off-path =====
    if (isL0) {
      if (i < NSTEP) {
        ZACC;
        MM2(bufA);
        GATEALL(2.0f, 0.5f, bufB);
        if (i + 1 < NSTEP) { XPROJ(xw, un, gxn); }
      }
    } else if (i >= 1) {
      ZACC;
      MM2(bufA);
      GATEALL(2.0f, 0.5f, bufB);
    }
    BAR();

    // ===== slot C: stage 3 =====
    if ((isL0 && i < NSTEP) || (!isL0 && i >= 1)) {
      ZACC;
      MM2(bufB);
      GATEALL(2.0f, 1.0f, bufA);
    }
    BAR();

    // ===== slot D: stage 4 -> h_new; L0 commits pipelined u/gx + seq reg =====
    if (isL0) {
      if (i < NSTEP) {
        ZACC;
        MM2(bufA);
        GATEFIN((i & 1) ? hq1 : hq0);
        if (i + 1 < NSTEP) {
          u[0] = un[0]; u[1] = un[1];
          gx[0] = gxn[0]; gx[1] = gxn[1];
          if (i + 2 < NSTEP) sq_nxt = sq_ld;
        }
      }
    } else if (i >= 1) {
      ZACC;
      MM2(bufA);
      GATEFIN(l1h);
    }
    BAR();
  }

  // ======================= classifier epilogue ===========================
  float* h1f = (float*)smem;  // [16][132] f32 (cols >= BPG are dead)
  if (!isL0) {
#pragma unroll
    for (int i2 = 0; i2 < 2; ++i2)
      *(f32x4*)(h1f + c * 132 + jb[i2]) = hst[i2];
  }
  __syncthreads();
  float* z1 = (float*)(smem + 16 * 132 * 4);  // [BPG][64] f32
  {
    int b = tid >> 5, o = tid & 31;
    if (b < BPG) {
#pragma unroll
      for (int hlf = 0; hlf < 2; ++hlf) {
        int oo = o + 32 * hlf;
        const float* wr = W1 + oo * 128;
        const float* hr = h1f + b * 132;
        float s = 0.f;
#pragma unroll
        for (int j = 0; j < 128; j += 4) {
          f32x4 wv = *(const f32x4*)(wr + j);
          f32x4 hv = *(const f32x4*)(hr + j);
          s += wv[0] * hv[0] + wv[1] * hv[1] + wv[2] * hv[2] + wv[3] * hv[3];
        }
        s += b1[oo];
        z1[b * 64 + oo] = fmaxf(s, 0.f);
      }
    }
  }
  __syncthreads();
  if (tid < BPG) {
    float s = b2[0];
#pragma unroll
    for (int o = 0; o < 64; ++o) s += z1[tid * 64 + o] * W2[o];
    out[bg * BPG + tid] = rcp_f(1.f + __expf(-s));
  }
}

extern "C" void kernel_launch(void* const* d_in, const int* in_sizes, int n_in,
                              void* d_out, int out_size, void* d_ws, size_t ws_size,
                              hipStream_t stream) {
  (void)in_sizes; (void)n_in; (void)out_size; (void)ws_size;
  const float* seq = (const float*)d_in[0];
  const float* ctx = (const float*)d_in[1];
  const float* tau0 = (const float*)d_in[2];
  const float* Win0 = (const float*)d_in[3];
  const float* Wrec0 = (const float*)d_in[4];
  const float* Wg0 = (const float*)d_in[5];
  const float* bg0 = (const float*)d_in[6];
  const float* tau1 = (const float*)d_in[7];
  const float* Win1 = (const float*)d_in[8];
  const float* Wrec1 = (const float*)d_in[9];
  const float* Wg1 = (const float*)d_in[10];
  const float* bg1 = (const float*)d_in[11];
  const float* W1 = (const float*)d_in[12];
  const float* b1 = (const float*)d_in[13];
  const float* W2 = (const float*)d_in[14];
  const float* b2 = (const float*)d_in[15];
  f16* W = (f16*)d_ws;  // 245760 B of packed fragments

  prep_kernel<<<480, 256, 0, stream>>>(Win0, Wrec0, Wg0, Win1, Wrec1, Wg1, W);
  ltc_kernel<<<512 / BPG, 512, 0, stream>>>(seq, ctx, tau0, bg0, tau1, bg1, W1,
                                            b1, W2, b2, W, (float*)d_out);
}

// Round 6
// 1826.542 us; speedup vs baseline: 1.1493x; 1.0468x over previous
//
#include <hip/hip_runtime.h>

// LTC RNN (LiquidNeuralNetwork): B=512, S=512, H=128, 2 layers, RK4.
// Round 8: PACKED-F32 GATE MATH on the round-3 structure (32 blocks x 512).
// Round-5 lesson: batch-split was null because gate VALU runs on all 64 lanes
// of the MFMA tile regardless of live cols -> per-CU issue unchanged. Active
// SIMDs are ~61% VALU + ~29% MFMA (serialized by lockstep) -> cut VALU count:
//  - gate chain rewritten on f32x2 pairs -> v_pk_{add,mul,fma}_f32 (full-rate
//    packed f32 on gfx90a+/gfx950). ~17 ops/el -> ~9 issue slots/el.
//  - gx folded into MM2's C-operand init (ga = gx + Wg_h*h), bg folded into
//    MMIO/XPROJ C-init -> kills the post-MFMA adds.
//  - stage-1 ksum = kk (assign) instead of zero+fma.
// Transcendentals (exp/rcp) stay scalar (no packed trans pipe).
// Kept: lag-1 layer pipeline, 4 slots/step, lgkm-only barriers, x-proj
// pipelined into slot B, f16 MFMA fragment pack, (512,1) bounds.

typedef _Float16 f16;
typedef _Float16 f16x4 __attribute__((ext_vector_type(4)));
typedef _Float16 f16x8 __attribute__((ext_vector_type(8)));
typedef float f32x2 __attribute__((ext_vector_type(2)));
typedef float f32x4 __attribute__((ext_vector_type(4)));

#define NSTEP 512
#define OFF_A0 0
#define OFF_A1 32768
#define OFF_AIO 65536
#define OFF_AX 98304
#define W_TOTAL 122880

// LDS byte offsets. hh buffers: [16 cols][136 f16] = 4352 B each.
#define HQ0 0
#define HQ1 4352
#define L0A 8704
#define L0B 13056
#define L1A 17408
#define L1B 21760
#define L1H 26112
#define XT0 30464
#define XT1 32768
#define SMEM_BYTES 35072

__device__ __forceinline__ float rcp_f(float x) { return __builtin_amdgcn_rcpf(x); }

#define FMA2(A, B, C) __builtin_elementwise_fma((A), (B), (C))
#define B2(X) ((f32x2){(X), (X)})
#define ZERO4 ((f32x4){0.f, 0.f, 0.f, 0.f})
#define ZERO2 ((f32x2){0.f, 0.f})

// packed tanh: 3 pk ops + 2 scalar exp chains + 2 rcp
__device__ __forceinline__ f32x2 tanh2_f(f32x2 z) {
  f32x2 zz = z + z;
  f32x2 e = {__expf(zz[0]), __expf(zz[1])};
  f32x2 d = e + 1.f;
  f32x2 r = {rcp_f(d[0]), rcp_f(d[1])};
  return FMA2(r, B2(-2.f), B2(1.f));
}
// packed sigmoid(t), t in [-1,1]: odd Taylor of 0.5+0.5*tanh(t/2), |err|<3e-6
__device__ __forceinline__ f32x2 sig2_f(f32x2 t) {
  f32x2 s = t * t;
  f32x2 p = FMA2(s, B2(2.1356861e-5f), B2(-2.1081349e-4f));
  p = FMA2(s, p, B2(2.0833333e-3f));
  p = FMA2(s, p, B2(-2.0833333e-2f));
  p = FMA2(s, p, B2(0.25f));
  return FMA2(t, p, B2(0.5f));
}

// lgkm-only barrier: LDS produce->consume needs lgkmcnt(0)+s_barrier only;
// does NOT drain vmcnt (seq prefetch stays in flight across barriers).
#define BAR()                                            \
  do {                                                   \
    asm volatile("s_waitcnt lgkmcnt(0)" ::: "memory");   \
    __builtin_amdgcn_s_barrier();                        \
  } while (0)

// Pack all recurrent-loop weights into f16 MFMA A-fragments.
// A-frag (16x16x32): A[m=lane&15][k=(lane>>4)*8+j], row-tile T = rows 16T..16T+15.
// A0 @0      [T8][sel2][kc4][lane64][j8]  sel0=Wg0 h-part, sel1=Wrec0
// A1 @32768  same                          sel0=Wg1 h-part, sel1=Wrec1
// AIO@65536  same                          sel0=Win1,       sel1=Wg1 x-part
// AX @98304  [T8][sel2][kc3][lane64][j8]  sel0=Win0,       sel1=Wg0 x-part (K=96)
__global__ __launch_bounds__(256) void prep_kernel(
    const float* __restrict__ Win0, const float* __restrict__ Wrec0,
    const float* __restrict__ Wg0, const float* __restrict__ Win1,
    const float* __restrict__ Wrec1, const float* __restrict__ Wg1,
    f16* __restrict__ W) {
  int i = blockIdx.x * 256 + threadIdx.x;
  if (i >= W_TOTAL) return;
  if (i < OFF_AX) {
    int sec = i >> 15;
    int r = i & 32767;
    int j = r & 7, lane = (r >> 3) & 63, kc = (r >> 9) & 3, sel = (r >> 11) & 1,
        w = (r >> 12) & 7;
    int row = w * 16 + (lane & 15);
    int k = kc * 32 + ((lane >> 4) << 3) + j;
    float v;
    if (sec == 0)
      v = sel ? Wrec0[row * 128 + k] : Wg0[row * 224 + 96 + k];
    else if (sec == 1)
      v = sel ? Wrec1[row * 128 + k] : Wg1[row * 256 + 128 + k];
    else
      v = sel ? Wg1[row * 256 + k] : Win1[row * 128 + k];
    W[i] = (f16)v;
  } else {
    int r = i - OFF_AX;
    int j = r & 7, lane = (r >> 3) & 63, g = r >> 9;
    int kc = g % 3, sg = g / 3;
    int sel = sg & 1, w = sg >> 1;
    int row = w * 16 + (lane & 15);
    int k = kc * 32 + ((lane >> 4) << 3) + j;
    W[i] = (f16)(sel ? Wg0[row * 224 + k] : Win0[row * 96 + k]);
  }
}

#define MFMA16(A, B, C) __builtin_amdgcn_mfma_f32_16x16x32_f16((A), (B), (C), 0, 0, 0)

// recurrent matvec, gx folded into gate C-init: ga = gx4 + Wg_h*h; ra = Wrec*h
#define MM2G(SRC)                                                   \
  {                                                                 \
    ga[0] = gx4[0]; ga[1] = gx4[1];                                 \
    ra[0] = ZERO4; ra[1] = ZERO4;                                   \
    const f16* bp_ = (SRC) + c * 136 + 8 * q;                       \
    _Pragma("unroll") for (int kc_ = 0; kc_ < 4; ++kc_) {           \
      f16x8 bf_ = *(const f16x8*)(bp_ + kc_ * 32);                  \
      ga[0] = MFMA16(awg[0][kc_], bf_, ga[0]);                      \
      ra[0] = MFMA16(awr[0][kc_], bf_, ra[0]);                      \
      ga[1] = MFMA16(awg[1][kc_], bf_, ga[1]);                      \
      ra[1] = MFMA16(awr[1][kc_], bf_, ra[1]);                      \
    }                                                               \
  }

// L1 io projection, bg folded into ra C-init: ga = Win1*h0; ra = bg + Wg1x*h0
#define MMIO_B(SRC)                                                 \
  {                                                                 \
    ga[0] = ZERO4; ga[1] = ZERO4;                                   \
    ra[0] = bgv4[0]; ra[1] = bgv4[1];                               \
    const f16* bp_ = (SRC) + c * 136 + 8 * q;                       \
    _Pragma("unroll") for (int kc_ = 0; kc_ < 4; ++kc_) {           \
      f16x8 bf_ = *(const f16x8*)(bp_ + kc_ * 32);                  \
      ga[0] = MFMA16(au[0][kc_], bf_, ga[0]);                       \
      ra[0] = MFMA16(ag2[0][kc_], bf_, ra[0]);                      \
      ga[1] = MFMA16(au[1][kc_], bf_, ga[1]);                       \
      ra[1] = MFMA16(ag2[1][kc_], bf_, ra[1]);                      \
    }                                                               \
  }

// L0 x-projection (K=96: 2 chunks from x-tile + ctx), bg folded:
// UD = Win0*x; GD = bg + Wg0x*x
#define XPROJ(XSRC, UD, GD)                                         \
  {                                                                 \
    f32x4 tg_[2], tr_[2];                                           \
    tg_[0] = ZERO4; tg_[1] = ZERO4;                                 \
    tr_[0] = bgv4[0]; tr_[1] = bgv4[1];                             \
    f16x8 bx0_ = *(const f16x8*)((XSRC) + c * 72 + 8 * q);          \
    f16x8 bx1_ = *(const f16x8*)((XSRC) + c * 72 + 32 + 8 * q);     \
    _Pragma("unroll") for (int i2_ = 0; i2_ < 2; ++i2_) {           \
      tg_[i2_] = MFMA16(au[i2_][0], bx0_, tg_[i2_]);                \
      tr_[i2_] = MFMA16(ag2[i2_][0], bx0_, tr_[i2_]);               \
      tg_[i2_] = MFMA16(au[i2_][1], bx1_, tg_[i2_]);                \
      tr_[i2_] = MFMA16(ag2[i2_][1], bx1_, tr_[i2_]);               \
      tg_[i2_] = MFMA16(au[i2_][2], bctx, tg_[i2_]);                \
      tr_[i2_] = MFMA16(ag2[i2_][2], bctx, tr_[i2_]);               \
      (UD)[i2_] = tg_[i2_];                                         \
      (GD)[i2_] = tr_[i2_];                                         \
    }                                                               \
  }

// RK stage body, packed pairs. Gate arg is complete in ga (gx folded).
// FIRST=1: ksum = kk (stage 1). Else ksum += WC*kk.
#define GATEP(WC, HC, DST, FIRST)                                   \
  _Pragma("unroll") for (int i2_ = 0; i2_ < 2; ++i2_) {             \
    f16x4 hv_;                                                      \
    _Pragma("unroll") for (int p_ = 0; p_ < 2; ++p_) {              \
      f32x2 z_ = p_ ? (f32x2){ga[i2_][2], ga[i2_][3]}               \
                    : (f32x2){ga[i2_][0], ga[i2_][1]};              \
      f32x2 rr_ = p_ ? (f32x2){ra[i2_][2], ra[i2_][3]}              \
                     : (f32x2){ra[i2_][0], ra[i2_][1]};             \
      f32x2 th_ = tanh2_f(z_);                                      \
      f32x2 gt_ = sig2_f(th_);                                      \
      f32x2 kk_ = FMA2(gt_, rr_,                                    \
                       FMA2(nitv2[i2_][p_], hhc2[i2_][p_], u2[i2_][p_])); \
      ksum2[i2_][p_] = (FIRST) ? kk_ : FMA2(B2(WC), kk_, ksum2[i2_][p_]); \
      f32x2 hn_ = FMA2(B2(HC), kk_, hst2[i2_][p_]);                 \
      hhc2[i2_][p_] = hn_;                                          \
      hv_[2 * p_] = (f16)hn_[0];                                    \
      hv_[2 * p_ + 1] = (f16)hn_[1];                                \
    }                                                               \
    *(f16x4*)((DST) + c * 136 + jb[i2_]) = hv_;                     \
  }

// RK stage 4: h_new = tanh(h + (ksum+kk)/6) -> state + next stage-1 eval.
#define GATEF(DST)                                                  \
  _Pragma("unroll") for (int i2_ = 0; i2_ < 2; ++i2_) {             \
    f16x4 hv_;                                                      \
    _Pragma("unroll") for (int p_ = 0; p_ < 2; ++p_) {              \
      f32x2 z_ = p_ ? (f32x2){ga[i2_][2], ga[i2_][3]}               \
                    : (f32x2){ga[i2_][0], ga[i2_][1]};              \
      f32x2 rr_ = p_ ? (f32x2){ra[i2_][2], ra[i2_][3]}              \
                     : (f32x2){ra[i2_][0], ra[i2_][1]};             \
      f32x2 th_ = tanh2_f(z_);                                      \
      f32x2 gt_ = sig2_f(th_);                                      \
      f32x2 kk_ = FMA2(gt_, rr_,                                    \
                       FMA2(nitv2[i2_][p_], hhc2[i2_][p_], u2[i2_][p_])); \
      f32x2 ks_ = ksum2[i2_][p_] + kk_;                             \
      f32x2 hn_ = tanh2_f(FMA2(B2(0.16666667f), ks_, hst2[i2_][p_])); \
      hst2[i2_][p_] = hn_;                                          \
      hhc2[i2_][p_] = hn_;                                          \
      hv_[2 * p_] = (f16)hn_[0];                                    \
      hv_[2 * p_ + 1] = (f16)hn_[1];                                \
    }                                                               \
    *(f16x4*)((DST) + c * 136 + jb[i2_]) = hv_;                     \
  }

__global__ __launch_bounds__(512, 1) void ltc_kernel(
    const float* __restrict__ seq, const float* __restrict__ ctx,
    const float* __restrict__ tau0p, const float* __restrict__ bg0p,
    const float* __restrict__ tau1p, const float* __restrict__ bg1p,
    const float* __restrict__ W1, const float* __restrict__ b1,
    const float* __restrict__ W2, const float* __restrict__ b2,
    const f16* __restrict__ W, float* __restrict__ out) {
  __shared__ __align__(16) char smem[SMEM_BYTES];
  f16* hq0 = (f16*)(smem + HQ0);
  f16* hq1 = (f16*)(smem + HQ1);
  f16* l0a = (f16*)(smem + L0A);
  f16* l0b = (f16*)(smem + L0B);
  f16* l1a = (f16*)(smem + L1A);
  f16* l1b = (f16*)(smem + L1B);
  f16* l1h = (f16*)(smem + L1H);
  f16* xt0 = (f16*)(smem + XT0);
  f16* xt1 = (f16*)(smem + XT1);

  const int tid = threadIdx.x;
  const int w8 = tid >> 6, lane = tid & 63;
  const int q = lane >> 4, c = lane & 15;
  const int wl = w8 & 3;
  const bool isL0 = (w8 < 4);
  const int bg = blockIdx.x;
  int jb[2];
  jb[0] = 32 * wl + 4 * q;
  jb[1] = jb[0] + 16;

  f16* bufA = isL0 ? l0a : l1a;
  f16* bufB = isL0 ? l0b : l1b;

  // ---- weight fragments -> VGPRs (held for whole kernel) ----
  f16x8 awg[2][4], awr[2][4], au[2][4], ag2[2][4];
  f16x8 bctx;
  if (isL0) {
#pragma unroll
    for (int i2 = 0; i2 < 2; ++i2) {
      int T = 2 * wl + i2;
#pragma unroll
      for (int kc = 0; kc < 4; ++kc) {
        awg[i2][kc] = *(const f16x8*)(W + OFF_A0 + (((T * 2 + 0) * 4 + kc) * 64 + lane) * 8);
        awr[i2][kc] = *(const f16x8*)(W + OFF_A0 + (((T * 2 + 1) * 4 + kc) * 64 + lane) * 8);
      }
#pragma unroll
      for (int kc = 0; kc < 3; ++kc) {
        au[i2][kc] = *(const f16x8*)(W + OFF_AX + (((T * 2 + 0) * 3 + kc) * 64 + lane) * 8);
        ag2[i2][kc] = *(const f16x8*)(W + OFF_AX + (((T * 2 + 1) * 3 + kc) * 64 + lane) * 8);
      }
      au[i2][3] = (f16x8)(f16)0.f;
      ag2[i2][3] = (f16x8)(f16)0.f;
    }
    const float* cp = ctx + (bg * 16 + c) * 32 + 8 * q;
#pragma unroll
    for (int j = 0; j < 8; ++j) bctx[j] = (f16)cp[j];
  } else {
#pragma unroll
    for (int i2 = 0; i2 < 2; ++i2) {
      int T = 2 * wl + i2;
#pragma unroll
      for (int kc = 0; kc < 4; ++kc) {
        awg[i2][kc] = *(const f16x8*)(W + OFF_A1 + (((T * 2 + 0) * 4 + kc) * 64 + lane) * 8);
        awr[i2][kc] = *(const f16x8*)(W + OFF_A1 + (((T * 2 + 1) * 4 + kc) * 64 + lane) * 8);
        au[i2][kc] = *(const f16x8*)(W + OFF_AIO + (((T * 2 + 0) * 4 + kc) * 64 + lane) * 8);
        ag2[i2][kc] = *(const f16x8*)(W + OFF_AIO + (((T * 2 + 1) * 4 + kc) * 64 + lane) * 8);
      }
    }
  }

  // per-lane params for the 8 owned rows (packed pairs, itv negated)
  const float* taup = isL0 ? tau0p : tau1p;
  const float* bgp = isL0 ? bg0p : bg1p;
  f32x2 nitv2[2][2];
  f32x4 bgv4[2];
#pragma unroll
  for (int i2 = 0; i2 < 2; ++i2)
#pragma unroll
    for (int r = 0; r < 4; ++r) {
      float t = taup[jb[i2] + r];
      nitv2[i2][r >> 1][r & 1] = -1.f / (logf(1.f + __expf(t)) + 1.f);
      bgv4[i2][r] = bgp[jb[i2] + r];
    }

  f32x2 hst2[2][2], hhc2[2][2], ksum2[2][2], u2[2][2];
  f32x4 ga[2], ra[2], gx4[2], un4[2], gxn4[2];
#pragma unroll
  for (int i2 = 0; i2 < 2; ++i2)
#pragma unroll
    for (int p = 0; p < 2; ++p) {
      hst2[i2][p] = ZERO2;
      hhc2[i2][p] = ZERO2;
      ksum2[i2][p] = ZERO2;
      u2[i2][p] = ZERO2;
    }
  gx4[0] = gx4[1] = ZERO4;
  un4[0] = un4[1] = ZERO4;
  gxn4[0] = gxn4[1] = ZERO4;

  // zero initial-state buffers: hq1 (h0 at t=-1) and l1h (h1 at t=-1)
  for (int j = tid; j < 2176; j += 512) {
    hq1[j] = (f16)0.f;
    l1h[j] = (f16)0.f;
  }
  // pre-stage x(0): 256 L0 threads, float4 each
  const int bs = tid >> 4, fp = tid & 15;
  const size_t seqrow = ((size_t)(bg * 16 + bs)) * NSTEP * 64 + 4 * fp;
  float4 sq_nxt = {0.f, 0.f, 0.f, 0.f};
  float4 sq_ld = sq_nxt;
  if (tid < 256) {
    float4 sv = *(const float4*)(seq + seqrow);
    *(f16x4*)(xt0 + bs * 72 + 4 * fp) =
        (f16x4){(f16)sv.x, (f16)sv.y, (f16)sv.z, (f16)sv.w};
    sq_nxt = *(const float4*)(seq + seqrow + 64);  // x(1)
  }
  __syncthreads();
  // u/gx for step 0 (pipeline warm-up)
  if (isL0) {
    XPROJ(xt0, un4, gxn4);
#pragma unroll
    for (int i2 = 0; i2 < 2; ++i2) {
      u2[i2][0] = (f32x2){un4[i2][0], un4[i2][1]};
      u2[i2][1] = (f32x2){un4[i2][2], un4[i2][3]};
      gx4[i2] = gxn4[i2];
    }
  }

#pragma unroll 1
  for (int i = 0; i <= NSTEP; ++i) {
    const f16* hprev = ((i + 1) & 1) ? hq1 : hq0;  // h0(t-1) buffer
    f16* xw = ((i + 1) & 1) ? xt1 : xt0;           // buffer for x(i+1)

    // ===== slot A: L0 stage1 (+stage x(i+1), issue x(i+2)) | L1 io + stage1
    if (isL0) {
      if (i < NSTEP) {
        if (i + 2 < NSTEP)
          sq_ld = *(const float4*)(seq + seqrow + (size_t)(i + 2) * 64);
        MM2G(hprev);  // stage 1 on h0(t-1) -- the critical prefix
        if (i + 1 < NSTEP)
          *(f16x4*)(xw + bs * 72 + 4 * fp) =
              (f16x4){(f16)sq_nxt.x, (f16)sq_nxt.y, (f16)sq_nxt.z, (f16)sq_nxt.w};
        GATEP(1.0f, 0.5f, bufA, 1);
      }
    } else {
      if (i >= 1) {
        MMIO_B(hprev);  // u1 = Win1*h0_new, g1x = bg + Wg1x*h0_new
#pragma unroll
        for (int i2 = 0; i2 < 2; ++i2) {
          u2[i2][0] = (f32x2){ga[i2][0], ga[i2][1]};
          u2[i2][1] = (f32x2){ga[i2][2], ga[i2][3]};
          gx4[i2] = ra[i2];
        }
        MM2G(l1h);  // stage 1 on h1(t-2)
        GATEP(1.0f, 0.5f, bufA, 1);
      }
    }
    BAR();

    // ===== slot B: stage 2 ; L0 also computes x-proj(i+1) off-path =====
    if (isL0) {
      if (i < NSTEP) {
        MM2G(bufA);
        GATEP(2.0f, 0.5f, bufB, 0);
        if (i + 1 < NSTEP) { XPROJ(xw, un4, gxn4); }
      }
    } else if (i >= 1) {
      MM2G(bufA);
      GATEP(2.0f, 0.5f, bufB, 0);
    }
    BAR();

    // ===== slot C: stage 3 =====
    if ((isL0 && i < NSTEP) || (!isL0 && i >= 1)) {
      MM2G(bufB);
      GATEP(2.0f, 1.0f, bufA, 0);
    }
    BAR();

    // ===== slot D: stage 4 -> h_new; L0 commits pipelined u/gx + seq reg =====
    if (isL0) {
      if (i < NSTEP) {
        MM2G(bufA);
        GATEF((i & 1) ? hq1 : hq0);
        if (i + 1 < NSTEP) {
#pragma unroll
          for (int i2 = 0; i2 < 2; ++i2) {
            u2[i2][0] = (f32x2){un4[i2][0], un4[i2][1]};
            u2[i2][1] = (f32x2){un4[i2][2], un4[i2][3]};
            gx4[i2] = gxn4[i2];
          }
          if (i + 2 < NSTEP) sq_nxt = sq_ld;
        }
      }
    } else if (i >= 1) {
      MM2G(bufA);
      GATEF(l1h);
    }
    BAR();
  }

  // ======================= classifier epilogue ===========================
  float* h1f = (float*)smem;  // [16][132] f32
  if (!isL0) {
#pragma unroll
    for (int i2 = 0; i2 < 2; ++i2)
#pragma unroll
      for (int p = 0; p < 2; ++p)
        *(f32x2*)(h1f + c * 132 + jb[i2] + 2 * p) = hst2[i2][p];
  }
  __syncthreads();
  float* z1 = (float*)(smem + 16 * 132 * 4);  // [16][64] f32
  {
    int b = tid >> 5, o = tid & 31;
#pragma unroll
    for (int hlf = 0; hlf < 2; ++hlf) {
      int oo = o + 32 * hlf;
      const float* wr = W1 + oo * 128;
      const float* hr = h1f + b * 132;
      float s = 0.f;
#pragma unroll
      for (int j = 0; j < 128; j += 4) {
        f32x4 wv = *(const f32x4*)(wr + j);
        f32x4 hv = *(const f32x4*)(hr + j);
        s += wv[0] * hv[0] + wv[1] * hv[1] + wv[2] * hv[2] + wv[3] * hv[3];
      }
      s += b1[oo];
      z1[b * 64 + oo] = fmaxf(s, 0.f);
    }
  }
  __syncthreads();
  if (tid < 16) {
    float s = b2[0];
#pragma unroll
    for (int o = 0; o < 64; ++o) s += z1[tid * 64 + o] * W2[o];
    out[bg * 16 + tid] = rcp_f(1.f + __expf(-s));
  }
}

extern "C" void kernel_launch(void* const* d_in, const int* in_sizes, int n_in,
                              void* d_out, int out_size, void* d_ws, size_t ws_size,
                              hipStream_t stream) {
  (void)in_sizes; (void)n_in; (void)out_size; (void)ws_size;
  const float* seq = (const float*)d_in[0];
  const float* ctx = (const float*)d_in[1];
  const float* tau0 = (const float*)d_in[2];
  const float* Win0 = (const float*)d_in[3];
  const float* Wrec0 = (const float*)d_in[4];
  const float* Wg0 = (const float*)d_in[5];
  const float* bg0 = (const float*)d_in[6];
  const float* tau1 = (const float*)d_in[7];
  const float* Win1 = (const float*)d_in[8];
  const float* Wrec1 = (const float*)d_in[9];
  const float* Wg1 = (const float*)d_in[10];
  const float* bg1 = (const float*)d_in[11];
  const float* W1 = (const float*)d_in[12];
  const float* b1 = (const float*)d_in[13];
  const float* W2 = (const float*)d_in[14];
  const float* b2 = (const float*)d_in[15];
  f16* W = (f16*)d_ws;  // 245760 B of packed fragments

  prep_kernel<<<480, 256, 0, stream>>>(Win0, Wrec0, Wg0, Win1, Wrec1, Wg1, W);
  ltc_kernel<<<32, 512, 0, stream>>>(seq, ctx, tau0, bg0, tau1, bg1, W1, b1, W2,
                                     b2, W, (float*)d_out);
}